// Round 12
// baseline (568.789 us; speedup 1.0000x reference)
//
#include <hip/hip_runtime.h>
#include <cstdint>

#define K_SEL 4768
#define CAND_CAP 16384
#define NBIN 4096
#define OVFCAP (CAND_CAP - 4096)

struct P5 { const float* p[5]; };

__device__ __forceinline__ unsigned fsortkey(float f) {
  unsigned b = __float_as_uint(f);
  return (b & 0x80000000u) ? ~b : (b | 0x80000000u);
}

// ==== fused per-(img,lvl) top-k: hist -> threshold -> gather -> exact select -> decode ==
__global__ __launch_bounds__(256) void k_topk(P5 obj, P5 del, const float* anchors,
                                              unsigned long long* ovf,
                                              float* boxP, unsigned long long* keyP) {
  int p = blockIdx.x; int img = p / 5, lvl = p % 5;
  int f = 256 >> lvl; int hw = f * f; int n = 3 * hw;
  int kk = (lvl == 4) ? 768 : 1000;
  int soff = lvl * 1000;
  int shift = 2 * (8 - lvl);
  __shared__ unsigned lh[NBIN];                  // histogram; reused as selSV/selIdx later
  __shared__ unsigned long long sk[4096];        // candidate keys
  __shared__ unsigned csum[256];
  __shared__ unsigned scnt;
  __shared__ int sB;
  const float* src = obj.p[lvl] + (size_t)img * n;
  const float4* src4 = (const float4*)src;
  int n4 = n >> 2;                               // n4 is a multiple of 64 for all levels
  int tid = threadIdx.x, lane = tid & 63;
  for (int b = tid; b < NBIN; b += 256) lh[b] = 0;
  if (tid == 0) scnt = 0;
  __syncthreads();
  // pass 1: histogram of sortable-logit top-12 bits
  for (int e = tid; e < n4; e += 256) {
    float4 v = src4[e];
    atomicAdd(&lh[fsortkey(v.x) >> 20], 1u);
    atomicAdd(&lh[fsortkey(v.y) >> 20], 1u);
    atomicAdd(&lh[fsortkey(v.z) >> 20], 1u);
    atomicAdd(&lh[fsortkey(v.w) >> 20], 1u);
  }
  __syncthreads();
  // threshold bin B: count(bin >= B) >= kk
  { unsigned s = 0;
#pragma unroll
    for (int k = 0; k < 16; ++k) s += lh[tid * 16 + k];
    csum[tid] = s; }
  __syncthreads();
  if (tid == 0) {
    unsigned acc = 0; int B = 0;
    for (int cc = 255; cc >= 0; --cc) {
      if (acc + csum[cc] >= (unsigned)kk) {
        for (int b = 15; b >= 0; --b) {
          acc += lh[cc * 16 + b];
          if (acc >= (unsigned)kk) { B = cc * 16 + b; break; }
        }
        break;
      }
      acc += csum[cc];
    }
    sB = B;
  }
  __syncthreads();
  int B = sB;
  unsigned long long* myovf = ovf + (size_t)p * OVFCAP;
  // pass 2: gather candidates into LDS (wave ballot + one LDS atomic per wave)
  for (int e = tid; e < n4; e += 256) {
    float4 v = src4[e];
    float vv[4] = {v.x, v.y, v.z, v.w};
#pragma unroll
    for (int j = 0; j < 4; ++j) {
      unsigned sv = fsortkey(vv[j]);
      bool pass = (int)(sv >> 20) >= B;
      unsigned long long m = __ballot(pass);
      if (m) {
        int leader = __ffsll(m) - 1;
        unsigned base = 0;
        if (lane == leader) base = atomicAdd(&scnt, (unsigned)__popcll(m));
        base = __shfl(base, leader);
        if (pass) {
          unsigned pos = base + (unsigned)__popcll(m & ((1ULL << lane) - 1ULL));
          int ee = e * 4 + j;
          int a = ee >> shift;                   // ee / hw
          int r = ee & (hw - 1);                 // ee % hw
          unsigned kidx = (unsigned)(r * 3 + a); // reference flatten order (y*W+x)*A + a
          unsigned long long key = ((unsigned long long)sv << 32) | (0xFFFFFFFFu - kidx);
          if (pos < 4096) sk[pos] = key;
          else if (pos < CAND_CAP) myovf[pos - 4096] = key;
        }
      }
    }
  }
  __syncthreads();
  int Cc = min((int)scnt, CAND_CAP);
  int stage = min(Cc, 4096);
  unsigned* selSV  = lh;                         // lh is dead: reuse
  unsigned* selIdx = lh + 2048;
  // pass 3: exact top-kk by rank counting (value desc, idx asc — unique keys)
  for (int c = tid; c < Cc; c += 256) {
    unsigned long long kc = (c < 4096) ? sk[c] : myovf[c - 4096];
    int rank = 0;
#pragma unroll 8
    for (int j = 0; j < stage; ++j) rank += (sk[j] > kc) ? 1 : 0;
    for (int j = stage; j < Cc; ++j) rank += (myovf[j - 4096] > kc) ? 1 : 0;
    if (rank < kk) { selSV[rank] = (unsigned)(kc >> 32); selIdx[rank] = 0xFFFFFFFFu - (unsigned)kc; }
  }
  __syncthreads();
  // pass 4: decode + clip + validity (numpy-faithful, no FMA contraction)
  const int aoffA[5] = {0, 196608, 245760, 258048, 261120};
  for (int i = tid; i < kk; i += 256) {
    unsigned k = selIdx[i];
    unsigned sv = selSV[i];
    int a = (int)(k % 3u); int r = (int)(k / 3u);
    int y = r >> (8 - lvl); int x = r & (f - 1);
    const float* dp = del.p[lvl] + (size_t)(img * 12 + a * 4) * hw + (size_t)y * f + x;
    float d0 = dp[0], d1 = dp[hw], d2 = dp[2 * hw], d3 = dp[3 * hw];
    const float* ar = anchors + (size_t)(aoffA[lvl] + (int)k) * 4;
    float a0 = ar[0], a1 = ar[1], a2 = ar[2], a3 = ar[3];
    float w = __fsub_rn(a2, a0), h = __fsub_rn(a3, a1);
    float cx = __fadd_rn(a0, __fmul_rn(0.5f, w));
    float cy = __fadd_rn(a1, __fmul_rn(0.5f, h));
    const float CLIP = 4.135166556742356f;       // log(1000/16)
    float dw = fminf(d2, CLIP), dh = fminf(d3, CLIP);
    float pcx = __fadd_rn(__fmul_rn(d0, w), cx);
    float pcy = __fadd_rn(__fmul_rn(d1, h), cy);
    float pw = __fmul_rn(expf(dw), w);
    float ph = __fmul_rn(expf(dh), h);
    float x1 = __fsub_rn(pcx, __fmul_rn(0.5f, pw));
    float y1 = __fsub_rn(pcy, __fmul_rn(0.5f, ph));
    float x2 = __fadd_rn(pcx, __fmul_rn(0.5f, pw));
    float y2 = __fadd_rn(pcy, __fmul_rn(0.5f, ph));
    float x1c = fminf(fmaxf(x1, 0.0f), 1024.0f);
    float y1c = fminf(fmaxf(y1, 0.0f), 1024.0f);
    float x2c = fminf(fmaxf(x2, 0.0f), 1024.0f);
    float y2c = fminf(fmaxf(y2, 0.0f), 1024.0f);
    bool valid = (__fsub_rn(x2c, x1c) >= 1e-3f) && (__fsub_rn(y2c, y1c) >= 1e-3f);
    int slot = img * K_SEL + soff + i;
    float* bp = boxP + (size_t)slot * 4;
    bp[0] = x1c; bp[1] = y1c; bp[2] = x2c; bp[3] = y2c;
    unsigned low = 0xFFFFFFFFu - (unsigned)(soff + i);    // pos asc tie-break, unique keys
    keyP[slot] = valid ? (((unsigned long long)sv << 32) | low) : (unsigned long long)low;
  }
}

// ------- global per-image stable sort by (logit desc, pos asc); emit rank-ordered boxes -
__global__ __launch_bounds__(256) void k_sortrank(const unsigned long long* keyP, const float* boxP,
                                                  float* sBox, int* sMeta) {
  __shared__ unsigned long long lk[K_SEL];
  int img = blockIdx.y;
  for (int t = threadIdx.x; t < K_SEL; t += 256) lk[t] = keyP[(size_t)img * K_SEL + t];
  __syncthreads();
  int i = blockIdx.x * 256 + threadIdx.x;
  if (i >= K_SEL) return;
  unsigned long long ki = lk[i];
  int rank = 0;
#pragma unroll 8
  for (int j = 0; j < K_SEL; ++j) rank += (lk[j] > ki) ? 1 : 0;
  int slot = img * K_SEL + i;
  const float* bp = boxP + (size_t)slot * 4;
  int oslot = img * K_SEL + rank;
  float* op = sBox + (size_t)oslot * 4;
  op[0] = bp[0]; op[1] = bp[1]; op[2] = bp[2]; op[3] = bp[3];
  sMeta[oslot] = (int)(0xFFFFFFFFu - (unsigned)ki);      // original selection pos 0..4767
}

// ---------------- IoU on offset boxes, bitwise matching reference -----------------------
__device__ __forceinline__ bool iou_gt(float rx1, float ry1, float rx2, float ry2, float rar,
                                       float cx1, float cy1, float cx2, float cy2, float car) {
  float ltx = fmaxf(rx1, cx1), lty = fmaxf(ry1, cy1);
  float rbx = fminf(rx2, cx2), rby = fminf(ry2, cy2);
  float wx = fmaxf(__fsub_rn(rbx, ltx), 0.0f);
  float wy = fmaxf(__fsub_rn(rby, lty), 0.0f);
  float inter = __fmul_rn(wx, wy);
  float denom = __fadd_rn(__fsub_rn(__fadd_rn(rar, car), inter), 1e-9f);
  return __fdiv_rn(inter, denom) > 0.7f;
}

// ---- PER-LEVEL upper-triangle suppression bitmask (<=1000 boxes, 16 words/row) ---------
__global__ __launch_bounds__(64) void k_lvlmask(const float* boxP, unsigned long long* gmask) {
  int img = blockIdx.y;
  int q = blockIdx.x;                        // 0..621 per image
  int lvl, q2;
  if (q < 544) { lvl = q / 136; q2 = q - lvl * 136; }
  else         { lvl = 4;       q2 = q - 544; }
  int kk = (lvl == 4) ? 768 : 1000;
  int nch = (kk + 63) >> 6;
  int rb = 0;
  while (q2 >= nch - rb) { q2 -= nch - rb; ++rb; }    // upper-tri (rb, cb>=rb)
  int cb = rb + q2;
  int t = threadIdx.x;
  float off = __fmul_rn((float)lvl, 1025.0f);
  const float4* b4 = (const float4*)boxP + (size_t)img * K_SEL + lvl * 1000;
  __shared__ float cx1[64], cy1[64], cx2[64], cy2[64], car[64];
  int j = cb * 64 + t;
  if (j < kk) {
    float4 bb = b4[j];
    float ox1 = __fadd_rn(bb.x, off), oy1 = __fadd_rn(bb.y, off);
    float ox2 = __fadd_rn(bb.z, off), oy2 = __fadd_rn(bb.w, off);
    cx1[t] = ox1; cy1[t] = oy1; cx2[t] = ox2; cy2[t] = oy2;
    car[t] = __fmul_rn(__fsub_rn(ox2, ox1), __fsub_rn(oy2, oy1));
  }
  __syncthreads();
  int i = rb * 64 + t;
  if (i >= kk) return;
  float4 bb = b4[i];
  float rx1 = __fadd_rn(bb.x, off), ry1 = __fadd_rn(bb.y, off);
  float rx2 = __fadd_rn(bb.z, off), ry2 = __fadd_rn(bb.w, off);
  float rar = __fmul_rn(__fsub_rn(rx2, rx1), __fsub_rn(ry2, ry1));
  unsigned long long bits = 0;
  int jmax = min(64, kk - cb * 64);
  int jj0 = (rb == cb) ? t + 1 : 0;
  for (int jj = jj0; jj < jmax; ++jj) {
    if (iou_gt(rx1, ry1, rx2, ry2, rar, cx1[jj], cy1[jj], cx2[jj], cy2[jj], car[jj]))
      bits |= (1ULL << jj);
  }
  gmask[((size_t)(img * 5 + lvl) * 1000 + i) * 16 + cb] = bits;
}

// ---- per-level greedy NMS: single wave; SPECULATIVE full-chunk row prefetch ------------
// Rows are 16 words (128 B): lane (g,w) loads word w of rows cbase+4k+g (16 loads, 32
// VGPRs), issued at chunk entry with keep-independent addresses. Serial loop hides the
// latency; fold is 16 register selects. One hidden vmcnt wait per chunk.
__global__ __launch_bounds__(64) void k_lvlnms(const unsigned long long* keyP,
                                               const unsigned long long* gmask,
                                               unsigned long long* keepw) {
  int p = blockIdx.x; int img = p / 5, lvl = p % 5;
  int kk = (lvl == 4) ? 768 : 1000;
  int nch = (kk + 63) >> 6;
  int t = threadIdx.x;
  int g = t >> 4, w = t & 15;
  const unsigned long long* gm = gmask + (size_t)p * 16000;
  const unsigned long long* kp = keyP + (size_t)img * K_SEL + lvl * 1000;
  unsigned long long rp = 0ULL;              // lane partial: OR over kept rows ≡ g (mod 4), word w
  int i0 = min(t, kk - 1);
  unsigned long long vpre = kp[i0];                       // prefetch chunk 0
  unsigned long long wpre = gm[(size_t)i0 * 16 + 0];
  for (int c = 0; c < nch; ++c) {
    int cbase = c * 64;
    unsigned long long spec[16];
#pragma unroll
    for (int k = 0; k < 16; ++k) {
      int row = cbase + 4 * k + g; row = min(row, kk - 1);
      spec[k] = gm[(size_t)row * 16 + w];                 // garbage words w<c: harmless (below)
    }
    int i = cbase + t;
    bool inb = i < kk;
    unsigned long long validm = __ballot(inb && (vpre >> 32) != 0ULL);
    unsigned long long wself = wpre;
    int cn = (c + 1 < nch) ? c + 1 : c;                   // prefetch next chunk
    int inx = min(cn * 64 + t, kk - 1);
    vpre = kp[inx];
    wpre = gm[(size_t)inx * 16 + cn];
    unsigned long long cur = __shfl(rp, c) | __shfl(rp, 16 + c) |
                             __shfl(rp, 32 + c) | __shfl(rp, 48 + c);
    unsigned long long candm = validm & ~cur;
    unsigned long long keepm = 0ULL;
    while (candm) {
      int b = __ffsll(candm) - 1;
      keepm |= (1ULL << b);
      candm &= candm - 1;
      candm &= ~__shfl(wself, b);                         // within-chunk suppression
    }
    if (t == 0) keepw[(size_t)p * 16 + c] = keepm;
    // fold from speculative registers: pure VALU
#pragma unroll
    for (int k = 0; k < 16; ++k)
      rp |= ((keepm >> (4 * k + g)) & 1ULL) ? spec[k] : 0ULL;
    // unwritten lower-tri words (w <= c) only pollute rp words <= c, which later chunks
    // never read (cur reads word c' > c). Clamped duplicate rows are never kept. Harmless.
  }
}

// ---- merge: walk global score order, compact first 1000 kept into d_out ----------------
__global__ __launch_bounds__(64) void k_merge(const float* sBox, const int* sMeta,
                                              const unsigned long long* keepw, float* out) {
  int img = blockIdx.x;
  int t = threadIdx.x;
  __shared__ unsigned long long kw[80];                 // 5 levels x 16 words
  for (int x = t; x < 80; x += 64) kw[x] = keepw[(size_t)img * 80 + x];
  __syncthreads();
  const int* meta = sMeta + (size_t)img * K_SEL;
  const float4* b4 = (const float4*)sBox + (size_t)img * K_SEL;
  float4* out4 = (float4*)out + (size_t)img * 1000;
  int outc = 0;
  int pos = meta[t];                                    // prefetch chunk 0
  for (int c = 0; c < 75 && outc < 1000; ++c) {
    int i = c * 64 + t;
    bool inb = i < K_SEL;
    int mypos = pos;
    int inx = min((c + 1) * 64 + t, K_SEL - 1);
    pos = meta[inx];                                    // prefetch next chunk
    int lvl = (mypos < 4000) ? mypos / 1000 : 4;
    int lpos = mypos - lvl * 1000;
    bool kept = inb && ((kw[lvl * 16 + (lpos >> 6)] >> (lpos & 63)) & 1ULL);
    unsigned long long keptm = __ballot(kept);
    int idx = outc + (int)__popcll(keptm & ((1ULL << t) - 1ULL));
    if (kept && idx < 1000) out4[idx] = b4[i];
    outc += (int)__popcll(keptm);
  }
  outc = min(outc, 1000);
  for (int s = outc + t; s < 1000; s += 64)
    out4[s] = make_float4(0.f, 0.f, 0.f, 0.f);          // zero-pad tail
}

extern "C" void kernel_launch(void* const* d_in, const int* in_sizes, int n_in,
                              void* d_out, int out_size, void* d_ws, size_t ws_size,
                              hipStream_t stream) {
  (void)in_sizes; (void)n_in;
  // setup_inputs() dict order is INTERLEAVED: obj_l0, delta_l0, obj_l1, delta_l1, ..., anchors
  P5 obj, del;
  for (int i = 0; i < 5; ++i) {
    obj.p[i] = (const float*)d_in[2 * i];
    del.p[i] = (const float*)d_in[2 * i + 1];
  }
  const float* anchors = (const float*)d_in[10];
  float* out = (float*)d_out;
  char* ws = (char*)d_ws;

  // ws layout (bytes)
  unsigned long long* ovf     = (unsigned long long*)(ws + 0);         // 40*12288*8 = 3932160
  float* boxP                 = (float*)(ws + 3932160);                // 610304 -> 4542464
  unsigned long long* keyP    = (unsigned long long*)(ws + 4542464);   // 305152 -> 4847616
  float* sBox                 = (float*)(ws + 4847616);                // 610304 -> 5457920
  int* sMeta                  = (int*)(ws + 5457920);                  // 152576 -> 5610496
  unsigned long long* keepw   = (unsigned long long*)(ws + 5610496);   // 5120   -> 5615616
  unsigned long long* gmask   = (unsigned long long*)(ws + 5615616);   // 40*1000*16*8 = 5120000 -> 10735616
  const size_t NEED = 10735616ULL;
  if (ws_size < NEED) { hipMemsetAsync(d_out, 0, (size_t)out_size * 4, stream); return; }

  k_topk    <<<40, 256, 0, stream>>>(obj, del, anchors, ovf, boxP, keyP);
  k_sortrank<<<dim3(19, 8), 256, 0, stream>>>(keyP, boxP, sBox, sMeta);
  k_lvlmask <<<dim3(622, 8), 64, 0, stream>>>(boxP, gmask);
  k_lvlnms  <<<40, 64, 0, stream>>>(keyP, gmask, keepw);
  k_merge   <<<8, 64, 0, stream>>>(sBox, sMeta, keepw, out);
}

// Round 13
// 392.288 us; speedup vs baseline: 1.4499x; 1.4499x over previous
//
#include <hip/hip_runtime.h>
#include <cstdint>

#define K_SEL 4768
#define CAND_CAP 16384
#define NBIN 4096
#define BUFCAP 512

struct P5 { const float* p[5]; };

__device__ __forceinline__ unsigned fsortkey(float f) {
  unsigned b = __float_as_uint(f);
  return (b & 0x80000000u) ? ~b : (b | 0x80000000u);
}

// ------- histogram of sortable-logit top-12 bits per (img,lvl): per-block partials ------
__global__ __launch_bounds__(256) void k_hist(P5 obj, unsigned* phist) {
  int p = blockIdx.y; int img = p / 5, lvl = p % 5;
  int f = 256 >> lvl; int n = 3 * f * f;
  __shared__ unsigned lh[NBIN];
  for (int b = threadIdx.x; b < NBIN; b += 256) lh[b] = 0;
  __syncthreads();
  int chunk = (n + gridDim.x - 1) / gridDim.x;
  int e0 = blockIdx.x * chunk, e1 = min(n, e0 + chunk);
  const float* src = obj.p[lvl] + (size_t)img * n;
  for (int e = e0 + threadIdx.x; e < e1; e += 256) {
    unsigned sv = fsortkey(src[e]);
    atomicAdd(&lh[sv >> 20], 1u);
  }
  __syncthreads();
  unsigned* dst = phist + ((size_t)(p * 8 + blockIdx.x)) * NBIN;
  for (int b = threadIdx.x; b < NBIN; b += 256) dst[b] = lh[b];   // unconditional: no pre-zero
}

// ------- sum partials, find threshold bin B (count(bin >= B) >= kk), zero cnt ----------
__global__ __launch_bounds__(256) void k_thresh(const unsigned* phist, int* Bthr, unsigned* cnt) {
  int p = blockIdx.x; int lvl = p % 5;
  unsigned kk = (lvl == 4) ? 768u : 1000u;
  __shared__ unsigned hsum[NBIN];
  __shared__ unsigned csum[256];
  int c = threadIdx.x;
  unsigned tot[16];
#pragma unroll
  for (int k = 0; k < 16; ++k) tot[k] = 0;
  for (int g = 0; g < 8; ++g) {
    const unsigned* hp = phist + ((size_t)(p * 8 + g)) * NBIN + c * 16;
#pragma unroll
    for (int k = 0; k < 16; ++k) tot[k] += hp[k];
  }
  unsigned s = 0;
#pragma unroll
  for (int k = 0; k < 16; ++k) { hsum[c * 16 + k] = tot[k]; s += tot[k]; }
  csum[c] = s;
  __syncthreads();
  if (c == 0) {
    unsigned acc = 0; int B = 0;
    for (int cc = 255; cc >= 0; --cc) {
      if (acc + csum[cc] >= kk) {
        for (int b = 15; b >= 0; --b) {
          acc += hsum[cc * 16 + b];
          if (acc >= kk) { B = cc * 16 + b; break; }
        }
        break;
      }
      acc += csum[cc];
    }
    Bthr[p] = B;
    cnt[p] = 0;                              // replaces ws memset for gather's counter
  }
}

// ------- gather candidates (bin >= B): LDS-buffered, ONE atomic per block --------------
__global__ __launch_bounds__(256) void k_gather(P5 obj, const int* Bthr, unsigned* cnt,
                                                unsigned long long* ck) {
  int p = blockIdx.y; int img = p / 5, lvl = p % 5;
  int f = 256 >> lvl; int hw = f * f; int n = 3 * hw;
  int B = Bthr[p];
  int shift = 2 * (8 - lvl);
  const float* src = obj.p[lvl] + (size_t)img * n;
  unsigned long long* dst = ck + (size_t)p * CAND_CAP;
  int tid = threadIdx.x;
  int lane = tid & 63, wv = tid >> 6;
  __shared__ unsigned long long buf[4][BUFCAP];
  __shared__ unsigned wTot[4];
  __shared__ unsigned blkBase;
  unsigned wc = 0;                             // wave-uniform running count
  for (int e = blockIdx.x * 256 + tid; e < n; e += gridDim.x * 256) {
    float v = src[e];
    unsigned sv = fsortkey(v);
    bool pass = (int)(sv >> 20) >= B;
    unsigned long long m = __ballot(pass);
    if (m) {
      if (pass) {
        unsigned pos = wc + (unsigned)__popcll(m & ((1ULL << lane) - 1ULL));
        int a = e >> shift;                    // e / hw
        int r = e & (hw - 1);                  // e % hw
        unsigned kidx = (unsigned)(r * 3 + a); // reference flatten order (y*W+x)*A + a
        unsigned long long key = ((unsigned long long)sv << 32) | (0xFFFFFFFFu - kidx);
        if (pos < BUFCAP) buf[wv][pos] = key;
        else {                                 // overflow safety (pathological skew only)
          unsigned gp = atomicAdd(&cnt[p], 1u);
          if (gp < CAND_CAP) dst[gp] = key;
        }
      }
      wc += (unsigned)__popcll(m);
    }
  }
  if (lane == 0) wTot[wv] = min(wc, (unsigned)BUFCAP);
  __syncthreads();
  if (tid == 0) {
    unsigned tot = wTot[0] + wTot[1] + wTot[2] + wTot[3];
    blkBase = tot ? atomicAdd(&cnt[p], tot) : 0u;
  }
  __syncthreads();
  unsigned myOff = blkBase;
  for (int x = 0; x < wv; ++x) myOff += wTot[x];
  unsigned wn = wTot[wv];
  for (unsigned j = lane; j < wn; j += 64) {
    unsigned gp = myOff + j;
    if (gp < CAND_CAP) dst[gp] = buf[wv][j];   // coalesced flush
  }
}

// ------- exact top-kk per level by rank counting, LDS-staged keys ----------------------
__global__ __launch_bounds__(256) void k_select(const unsigned* cnt, const unsigned long long* ck,
                                                unsigned* selSV, unsigned* selIdx) {
  int p = blockIdx.y; int img = p / 5, lvl = p % 5;
  int Cc = min((int)cnt[p], CAND_CAP);
  if (blockIdx.x * 256 >= Cc) return;
  int kk = (lvl == 4) ? 768 : 1000;
  int soff = lvl * 1000;
  const unsigned long long* keys = ck + (size_t)p * CAND_CAP;
  __shared__ unsigned long long sk[4096];
  int stage = min(Cc, 4096);
  for (int j = threadIdx.x; j < stage; j += 256) sk[j] = keys[j];
  __syncthreads();
  int c = blockIdx.x * 256 + threadIdx.x;
  if (c >= Cc) return;
  unsigned long long kc = keys[c];
  int rank = 0;
#pragma unroll 8
  for (int j = 0; j < stage; ++j) rank += (sk[j] > kc) ? 1 : 0;
  for (int j = stage; j < Cc; ++j) rank += (keys[j] > kc) ? 1 : 0;
  if (rank < kk) {
    int slot = img * K_SEL + soff + rank;
    selSV[slot]  = (unsigned)(kc >> 32);
    selIdx[slot] = 0xFFFFFFFFu - (unsigned)kc;
  }
}

// ---------------- decode + clip + validity for the 4768 selected per image --------------
__global__ __launch_bounds__(256) void k_decode(P5 del, const float* anchors,
                                                const unsigned* selSV, const unsigned* selIdx,
                                                float* boxP, unsigned long long* keyP) {
  int i = blockIdx.x * 256 + threadIdx.x;
  if (i >= K_SEL) return;
  int img = blockIdx.y;
  int lvl = (i < 4000) ? (i / 1000) : 4;
  int f = 256 >> lvl, hw = f * f;
  const int aoffA[5] = {0, 196608, 245760, 258048, 261120};
  int slot = img * K_SEL + i;
  unsigned k = selIdx[slot];
  unsigned sv = selSV[slot];
  int a = (int)(k % 3u); int r = (int)(k / 3u);
  int y = r >> (8 - lvl); int x = r & (f - 1);
  const float* dp = del.p[lvl] + (size_t)(img * 12 + a * 4) * hw + (size_t)y * f + x;
  float d0 = dp[0], d1 = dp[hw], d2 = dp[2 * hw], d3 = dp[3 * hw];
  const float* ar = anchors + (size_t)(aoffA[lvl] + (int)k) * 4;
  float a0 = ar[0], a1 = ar[1], a2 = ar[2], a3 = ar[3];
  // numpy-faithful, no FMA contraction
  float w = __fsub_rn(a2, a0), h = __fsub_rn(a3, a1);
  float cx = __fadd_rn(a0, __fmul_rn(0.5f, w));
  float cy = __fadd_rn(a1, __fmul_rn(0.5f, h));
  const float CLIP = 4.135166556742356f;     // log(1000/16)
  float dw = fminf(d2, CLIP), dh = fminf(d3, CLIP);
  float pcx = __fadd_rn(__fmul_rn(d0, w), cx);
  float pcy = __fadd_rn(__fmul_rn(d1, h), cy);
  float pw = __fmul_rn(expf(dw), w);
  float ph = __fmul_rn(expf(dh), h);
  float x1 = __fsub_rn(pcx, __fmul_rn(0.5f, pw));
  float y1 = __fsub_rn(pcy, __fmul_rn(0.5f, ph));
  float x2 = __fadd_rn(pcx, __fmul_rn(0.5f, pw));
  float y2 = __fadd_rn(pcy, __fmul_rn(0.5f, ph));
  float x1c = fminf(fmaxf(x1, 0.0f), 1024.0f);
  float y1c = fminf(fmaxf(y1, 0.0f), 1024.0f);
  float x2c = fminf(fmaxf(x2, 0.0f), 1024.0f);
  float y2c = fminf(fmaxf(y2, 0.0f), 1024.0f);
  bool valid = (__fsub_rn(x2c, x1c) >= 1e-3f) && (__fsub_rn(y2c, y1c) >= 1e-3f);
  float* bp = boxP + (size_t)slot * 4;
  bp[0] = x1c; bp[1] = y1c; bp[2] = x2c; bp[3] = y2c;
  unsigned low = 0xFFFFFFFFu - (unsigned)i;   // pos asc tie-break, unique keys
  keyP[slot] = valid ? (((unsigned long long)sv << 32) | low) : (unsigned long long)low;
}

// ------- global per-image stable sort by (logit desc, pos asc); emit rank-ordered boxes -
__global__ __launch_bounds__(256) void k_sortrank(const unsigned long long* keyP, const float* boxP,
                                                  float* sBox, int* sMeta) {
  __shared__ unsigned long long lk[K_SEL];
  int img = blockIdx.y;
  for (int t = threadIdx.x; t < K_SEL; t += 256) lk[t] = keyP[(size_t)img * K_SEL + t];
  __syncthreads();
  int i = blockIdx.x * 256 + threadIdx.x;
  if (i >= K_SEL) return;
  unsigned long long ki = lk[i];
  int rank = 0;
#pragma unroll 8
  for (int j = 0; j < K_SEL; ++j) rank += (lk[j] > ki) ? 1 : 0;
  int slot = img * K_SEL + i;
  const float* bp = boxP + (size_t)slot * 4;
  int oslot = img * K_SEL + rank;
  float* op = sBox + (size_t)oslot * 4;
  op[0] = bp[0]; op[1] = bp[1]; op[2] = bp[2]; op[3] = bp[3];
  sMeta[oslot] = (int)(0xFFFFFFFFu - (unsigned)ki);      // original selection pos 0..4767
}

// ---------------- IoU on offset boxes, bitwise matching reference -----------------------
__device__ __forceinline__ bool iou_gt(float rx1, float ry1, float rx2, float ry2, float rar,
                                       float cx1, float cy1, float cx2, float cy2, float car) {
  float ltx = fmaxf(rx1, cx1), lty = fmaxf(ry1, cy1);
  float rbx = fminf(rx2, cx2), rby = fminf(ry2, cy2);
  float wx = fmaxf(__fsub_rn(rbx, ltx), 0.0f);
  float wy = fmaxf(__fsub_rn(rby, lty), 0.0f);
  float inter = __fmul_rn(wx, wy);
  float denom = __fadd_rn(__fsub_rn(__fadd_rn(rar, car), inter), 1e-9f);
  return __fdiv_rn(inter, denom) > 0.7f;
}

// ---- PER-LEVEL upper-triangle suppression bitmask (<=1000 boxes, 16 words/row) ---------
// Suppression is intra-level only (1025*lvl offset => cross-level IoU == 0).
__global__ __launch_bounds__(64) void k_lvlmask(const float* boxP, unsigned long long* gmask) {
  int img = blockIdx.y;
  int q = blockIdx.x;                        // 0..621 per image
  int lvl, q2;
  if (q < 544) { lvl = q / 136; q2 = q - lvl * 136; }
  else         { lvl = 4;       q2 = q - 544; }
  int kk = (lvl == 4) ? 768 : 1000;
  int nch = (kk + 63) >> 6;
  int rb = 0;
  while (q2 >= nch - rb) { q2 -= nch - rb; ++rb; }    // upper-tri (rb, cb>=rb)
  int cb = rb + q2;
  int t = threadIdx.x;
  float off = __fmul_rn((float)lvl, 1025.0f);
  const float4* b4 = (const float4*)boxP + (size_t)img * K_SEL + lvl * 1000;
  __shared__ float cx1[64], cy1[64], cx2[64], cy2[64], car[64];
  int j = cb * 64 + t;
  if (j < kk) {
    float4 bb = b4[j];
    float ox1 = __fadd_rn(bb.x, off), oy1 = __fadd_rn(bb.y, off);
    float ox2 = __fadd_rn(bb.z, off), oy2 = __fadd_rn(bb.w, off);
    cx1[t] = ox1; cy1[t] = oy1; cx2[t] = ox2; cy2[t] = oy2;
    car[t] = __fmul_rn(__fsub_rn(ox2, ox1), __fsub_rn(oy2, oy1));
  }
  __syncthreads();
  int i = rb * 64 + t;
  if (i >= kk) return;
  float4 bb = b4[i];
  float rx1 = __fadd_rn(bb.x, off), ry1 = __fadd_rn(bb.y, off);
  float rx2 = __fadd_rn(bb.z, off), ry2 = __fadd_rn(bb.w, off);
  float rar = __fmul_rn(__fsub_rn(rx2, rx1), __fsub_rn(ry2, ry1));
  unsigned long long bits = 0;
  int jmax = min(64, kk - cb * 64);
  int jj0 = (rb == cb) ? t + 1 : 0;
  for (int jj = jj0; jj < jmax; ++jj) {
    if (iou_gt(rx1, ry1, rx2, ry2, rar, cx1[jj], cy1[jj], cx2[jj], cy2[jj], car[jj]))
      bits |= (1ULL << jj);
  }
  gmask[((size_t)(img * 5 + lvl) * 1000 + i) * 16 + cb] = bits;
}

// ---- per-level greedy NMS: single wave; SPECULATIVE full-chunk row prefetch ------------
// Rows are 16 words (128 B): lane (g,w) loads word w of rows cbase+4k+g (16 loads, 32
// VGPRs), issued at chunk entry with keep-independent addresses. Serial loop hides the
// latency; fold is 16 register selects. One hideable vmcnt wait per chunk.
__global__ __launch_bounds__(64) void k_lvlnms(const unsigned long long* keyP,
                                               const unsigned long long* gmask,
                                               unsigned long long* keepw) {
  int p = blockIdx.x; int img = p / 5, lvl = p % 5;
  int kk = (lvl == 4) ? 768 : 1000;
  int nch = (kk + 63) >> 6;
  int t = threadIdx.x;
  int g = t >> 4, w = t & 15;
  const unsigned long long* gm = gmask + (size_t)p * 16000;
  const unsigned long long* kp = keyP + (size_t)img * K_SEL + lvl * 1000;
  unsigned long long rp = 0ULL;              // lane partial: OR over kept rows ≡ g (mod 4), word w
  int i0 = min(t, kk - 1);
  unsigned long long vpre = kp[i0];                       // prefetch chunk 0
  unsigned long long wpre = gm[(size_t)i0 * 16 + 0];
  for (int c = 0; c < nch; ++c) {
    int cbase = c * 64;
    unsigned long long spec[16];
#pragma unroll
    for (int k = 0; k < 16; ++k) {
      int row = cbase + 4 * k + g; row = min(row, kk - 1);
      spec[k] = gm[(size_t)row * 16 + w];                 // garbage words w<=c: harmless (below)
    }
    int i = cbase + t;
    bool inb = i < kk;
    unsigned long long validm = __ballot(inb && (vpre >> 32) != 0ULL);
    unsigned long long wself = wpre;
    int cn = (c + 1 < nch) ? c + 1 : c;                   // prefetch next chunk
    int inx = min(cn * 64 + t, kk - 1);
    vpre = kp[inx];
    wpre = gm[(size_t)inx * 16 + cn];
    unsigned long long cur = __shfl(rp, c) | __shfl(rp, 16 + c) |
                             __shfl(rp, 32 + c) | __shfl(rp, 48 + c);
    unsigned long long candm = validm & ~cur;
    unsigned long long keepm = 0ULL;
    while (candm) {
      int b = __ffsll(candm) - 1;
      keepm |= (1ULL << b);
      candm &= candm - 1;
      candm &= ~__shfl(wself, b);                         // within-chunk suppression
    }
    if (t == 0) keepw[(size_t)p * 16 + c] = keepm;
    // fold from speculative registers: pure VALU
#pragma unroll
    for (int k = 0; k < 16; ++k)
      rp |= ((keepm >> (4 * k + g)) & 1ULL) ? spec[k] : 0ULL;
    // unwritten lower-tri words (w <= c) only pollute rp words <= c, which later chunks
    // never read (cur reads word c' > c). Clamped duplicate rows are never kept. Harmless.
  }
}

// ---- merge: walk global score order, compact first 1000 kept into d_out ----------------
__global__ __launch_bounds__(64) void k_merge(const float* sBox, const int* sMeta,
                                              const unsigned long long* keepw, float* out) {
  int img = blockIdx.x;
  int t = threadIdx.x;
  __shared__ unsigned long long kw[80];                 // 5 levels x 16 words
  for (int x = t; x < 80; x += 64) kw[x] = keepw[(size_t)img * 80 + x];
  __syncthreads();
  const int* meta = sMeta + (size_t)img * K_SEL;
  const float4* b4 = (const float4*)sBox + (size_t)img * K_SEL;
  float4* out4 = (float4*)out + (size_t)img * 1000;
  int outc = 0;
  int pos = meta[t];                                    // prefetch chunk 0
  for (int c = 0; c < 75 && outc < 1000; ++c) {
    int i = c * 64 + t;
    bool inb = i < K_SEL;
    int mypos = pos;
    int inx = min((c + 1) * 64 + t, K_SEL - 1);
    pos = meta[inx];                                    // prefetch next chunk
    int lvl = (mypos < 4000) ? mypos / 1000 : 4;
    int lpos = mypos - lvl * 1000;
    bool kept = inb && ((kw[lvl * 16 + (lpos >> 6)] >> (lpos & 63)) & 1ULL);
    unsigned long long keptm = __ballot(kept);
    int idx = outc + (int)__popcll(keptm & ((1ULL << t) - 1ULL));
    if (kept && idx < 1000) out4[idx] = b4[i];
    outc += (int)__popcll(keptm);
  }
  outc = min(outc, 1000);
  for (int s = outc + t; s < 1000; s += 64)
    out4[s] = make_float4(0.f, 0.f, 0.f, 0.f);          // zero-pad tail
}

extern "C" void kernel_launch(void* const* d_in, const int* in_sizes, int n_in,
                              void* d_out, int out_size, void* d_ws, size_t ws_size,
                              hipStream_t stream) {
  (void)in_sizes; (void)n_in;
  // setup_inputs() dict order is INTERLEAVED: obj_l0, delta_l0, obj_l1, delta_l1, ..., anchors
  P5 obj, del;
  for (int i = 0; i < 5; ++i) {
    obj.p[i] = (const float*)d_in[2 * i];
    del.p[i] = (const float*)d_in[2 * i + 1];
  }
  const float* anchors = (const float*)d_in[10];
  float* out = (float*)d_out;
  char* ws = (char*)d_ws;

  // ws layout (bytes)
  unsigned* cnt               = (unsigned*)(ws + 0);                   // 160
  int* Bthr                   = (int*)(ws + 192);                      // 160
  unsigned long long* candK   = (unsigned long long*)(ws + 512);       // 40*16384*8 = 5242880 -> 5243392
  unsigned* selSV             = (unsigned*)(ws + 5243392);             // 152576 -> 5395968
  unsigned* selIdx            = (unsigned*)(ws + 5395968);             // 152576 -> 5548544
  float* boxP                 = (float*)(ws + 5548544);                // 610304 -> 6158848
  unsigned long long* keyP    = (unsigned long long*)(ws + 6158848);   // 305152 -> 6464000
  float* sBox                 = (float*)(ws + 6464000);                // 610304 -> 7074304
  int* sMeta                  = (int*)(ws + 7074304);                  // 152576 -> 7226880
  unsigned long long* keepw   = (unsigned long long*)(ws + 7226880);   // 40*16*8 = 5120 -> 7232000
  unsigned long long* gmask   = (unsigned long long*)(ws + 7232000);   // 40*1000*16*8 = 5120000 -> 12352000
  unsigned* phist             = (unsigned*)(ws + 7232000);             // overlay on gmask (dead before k_lvlmask)
  const size_t NEED = 12474880ULL;
  if (ws_size < NEED) { hipMemsetAsync(d_out, 0, (size_t)out_size * 4, stream); return; }

  k_hist    <<<dim3(8, 40), 256, 0, stream>>>(obj, phist);
  k_thresh  <<<40, 256, 0, stream>>>(phist, Bthr, cnt);
  k_gather  <<<dim3(32, 40), 256, 0, stream>>>(obj, Bthr, cnt, candK);
  k_select  <<<dim3(64, 40), 256, 0, stream>>>(cnt, candK, selSV, selIdx);
  k_decode  <<<dim3(19, 8), 256, 0, stream>>>(del, anchors, selSV, selIdx, boxP, keyP);
  k_sortrank<<<dim3(19, 8), 256, 0, stream>>>(keyP, boxP, sBox, sMeta);
  k_lvlmask <<<dim3(622, 8), 64, 0, stream>>>(boxP, gmask);
  k_lvlnms  <<<40, 64, 0, stream>>>(keyP, gmask, keepw);
  k_merge   <<<8, 64, 0, stream>>>(sBox, sMeta, keepw, out);
}

// Round 14
// 326.844 us; speedup vs baseline: 1.7402x; 1.2002x over previous
//
#include <hip/hip_runtime.h>
#include <cstdint>

#define K_SEL 4768
#define CAND_CAP 16384
#define NBIN 4096
#define BUFCAP 512

struct P5 { const float* p[5]; };

__device__ __forceinline__ unsigned fsortkey(float f) {
  unsigned b = __float_as_uint(f);
  return (b & 0x80000000u) ? ~b : (b | 0x80000000u);
}

// ------- histogram of sortable-logit top-12 bits per (img,lvl): per-block partials ------
__global__ __launch_bounds__(256) void k_hist(P5 obj, unsigned* phist) {
  int p = blockIdx.y; int img = p / 5, lvl = p % 5;
  int f = 256 >> lvl; int n = 3 * f * f;
  __shared__ unsigned lh[NBIN];
  for (int b = threadIdx.x; b < NBIN; b += 256) lh[b] = 0;
  __syncthreads();
  const float4* src4 = (const float4*)(obj.p[lvl] + (size_t)img * n);
  int n4 = n >> 2;
  int chunk = (n4 + gridDim.x - 1) / gridDim.x;
  int e0 = blockIdx.x * chunk, e1 = min(n4, e0 + chunk);
  for (int e = e0 + threadIdx.x; e < e1; e += 256) {
    float4 v = src4[e];
    atomicAdd(&lh[fsortkey(v.x) >> 20], 1u);
    atomicAdd(&lh[fsortkey(v.y) >> 20], 1u);
    atomicAdd(&lh[fsortkey(v.z) >> 20], 1u);
    atomicAdd(&lh[fsortkey(v.w) >> 20], 1u);
  }
  __syncthreads();
  unsigned* dst = phist + ((size_t)(p * 8 + blockIdx.x)) * NBIN;
  for (int b = threadIdx.x; b < NBIN; b += 256) dst[b] = lh[b];   // unconditional: no pre-zero
}

// ------- sum partials, find threshold bin B (count(bin >= B) >= kk), zero cnt ----------
__global__ __launch_bounds__(256) void k_thresh(const unsigned* phist, int* Bthr, unsigned* cnt) {
  int p = blockIdx.x; int lvl = p % 5;
  unsigned kk = (lvl == 4) ? 768u : 1000u;
  __shared__ unsigned hsum[NBIN];
  __shared__ unsigned csum[256];
  int c = threadIdx.x;
  unsigned tot[16];
#pragma unroll
  for (int k = 0; k < 16; ++k) tot[k] = 0;
  for (int g = 0; g < 8; ++g) {
    const unsigned* hp = phist + ((size_t)(p * 8 + g)) * NBIN + c * 16;
#pragma unroll
    for (int k = 0; k < 16; ++k) tot[k] += hp[k];
  }
  unsigned s = 0;
#pragma unroll
  for (int k = 0; k < 16; ++k) { hsum[c * 16 + k] = tot[k]; s += tot[k]; }
  csum[c] = s;
  __syncthreads();
  if (c == 0) {
    unsigned acc = 0; int B = 0;
    for (int cc = 255; cc >= 0; --cc) {
      if (acc + csum[cc] >= kk) {
        for (int b = 15; b >= 0; --b) {
          acc += hsum[cc * 16 + b];
          if (acc >= kk) { B = cc * 16 + b; break; }
        }
        break;
      }
      acc += csum[cc];
    }
    Bthr[p] = B;
    cnt[p] = 0;                              // replaces ws memset for gather's counter
  }
}

// ------- gather candidates (bin >= B): float4 reads, LDS-buffered, ONE atomic per block -
__global__ __launch_bounds__(256) void k_gather(P5 obj, const int* Bthr, unsigned* cnt,
                                                unsigned long long* ck) {
  int p = blockIdx.y; int img = p / 5, lvl = p % 5;
  int f = 256 >> lvl; int hw = f * f; int n = 3 * hw;
  int B = Bthr[p];
  int shift = 2 * (8 - lvl);
  const float4* src4 = (const float4*)(obj.p[lvl] + (size_t)img * n);
  int n4 = n >> 2;
  unsigned long long* dst = ck + (size_t)p * CAND_CAP;
  int tid = threadIdx.x;
  int lane = tid & 63, wv = tid >> 6;
  __shared__ unsigned long long buf[4][BUFCAP];
  __shared__ unsigned wTot[4];
  __shared__ unsigned blkBase;
  unsigned wc = 0;                             // wave-uniform running count
  for (int e = blockIdx.x * 256 + tid; e < n4; e += gridDim.x * 256) {
    float4 v = src4[e];
    float vv[4] = {v.x, v.y, v.z, v.w};
#pragma unroll
    for (int j = 0; j < 4; ++j) {
      unsigned sv = fsortkey(vv[j]);
      bool pass = (int)(sv >> 20) >= B;
      unsigned long long m = __ballot(pass);
      if (m) {
        if (pass) {
          unsigned pos = wc + (unsigned)__popcll(m & ((1ULL << lane) - 1ULL));
          int ee = e * 4 + j;
          int a = ee >> shift;                 // ee / hw
          int r = ee & (hw - 1);               // ee % hw
          unsigned kidx = (unsigned)(r * 3 + a); // reference flatten order (y*W+x)*A + a
          unsigned long long key = ((unsigned long long)sv << 32) | (0xFFFFFFFFu - kidx);
          if (pos < BUFCAP) buf[wv][pos] = key;
          else {                               // overflow safety (pathological skew only)
            unsigned gp = atomicAdd(&cnt[p], 1u);
            if (gp < CAND_CAP) dst[gp] = key;
          }
        }
        wc += (unsigned)__popcll(m);
      }
    }
  }
  if (lane == 0) wTot[wv] = min(wc, (unsigned)BUFCAP);
  __syncthreads();
  if (tid == 0) {
    unsigned tot = wTot[0] + wTot[1] + wTot[2] + wTot[3];
    blkBase = tot ? atomicAdd(&cnt[p], tot) : 0u;
  }
  __syncthreads();
  unsigned myOff = blkBase;
  for (int x = 0; x < wv; ++x) myOff += wTot[x];
  unsigned wn = wTot[wv];
  for (unsigned j = lane; j < wn; j += 64) {
    unsigned gp = myOff + j;
    if (gp < CAND_CAP) dst[gp] = buf[wv][j];   // coalesced flush
  }
}

// ------- exact top-kk per level by rank counting, LDS-staged keys ----------------------
__global__ __launch_bounds__(256) void k_select(const unsigned* cnt, const unsigned long long* ck,
                                                unsigned* selSV, unsigned* selIdx) {
  int p = blockIdx.y; int img = p / 5, lvl = p % 5;
  int Cc = min((int)cnt[p], CAND_CAP);
  if (blockIdx.x * 256 >= Cc) return;
  int kk = (lvl == 4) ? 768 : 1000;
  int soff = lvl * 1000;
  const unsigned long long* keys = ck + (size_t)p * CAND_CAP;
  __shared__ unsigned long long sk[4096];
  int stage = min(Cc, 4096);
  for (int j = threadIdx.x; j < stage; j += 256) sk[j] = keys[j];
  __syncthreads();
  int c = blockIdx.x * 256 + threadIdx.x;
  if (c >= Cc) return;
  unsigned long long kc = keys[c];
  int rank = 0;
#pragma unroll 8
  for (int j = 0; j < stage; ++j) rank += (sk[j] > kc) ? 1 : 0;
  for (int j = stage; j < Cc; ++j) rank += (keys[j] > kc) ? 1 : 0;
  if (rank < kk) {
    int slot = img * K_SEL + soff + rank;
    selSV[slot]  = (unsigned)(kc >> 32);
    selIdx[slot] = 0xFFFFFFFFu - (unsigned)kc;
  }
}

// ---------------- decode + clip + validity for the 4768 selected per image --------------
__global__ __launch_bounds__(256) void k_decode(P5 del, const float* anchors,
                                                const unsigned* selSV, const unsigned* selIdx,
                                                float* boxP, unsigned long long* keyP) {
  int i = blockIdx.x * 256 + threadIdx.x;
  if (i >= K_SEL) return;
  int img = blockIdx.y;
  int lvl = (i < 4000) ? (i / 1000) : 4;
  int f = 256 >> lvl, hw = f * f;
  const int aoffA[5] = {0, 196608, 245760, 258048, 261120};
  int slot = img * K_SEL + i;
  unsigned k = selIdx[slot];
  unsigned sv = selSV[slot];
  int a = (int)(k % 3u); int r = (int)(k / 3u);
  int y = r >> (8 - lvl); int x = r & (f - 1);
  const float* dp = del.p[lvl] + (size_t)(img * 12 + a * 4) * hw + (size_t)y * f + x;
  float d0 = dp[0], d1 = dp[hw], d2 = dp[2 * hw], d3 = dp[3 * hw];
  const float* ar = anchors + (size_t)(aoffA[lvl] + (int)k) * 4;
  float a0 = ar[0], a1 = ar[1], a2 = ar[2], a3 = ar[3];
  // numpy-faithful, no FMA contraction
  float w = __fsub_rn(a2, a0), h = __fsub_rn(a3, a1);
  float cx = __fadd_rn(a0, __fmul_rn(0.5f, w));
  float cy = __fadd_rn(a1, __fmul_rn(0.5f, h));
  const float CLIP = 4.135166556742356f;     // log(1000/16)
  float dw = fminf(d2, CLIP), dh = fminf(d3, CLIP);
  float pcx = __fadd_rn(__fmul_rn(d0, w), cx);
  float pcy = __fadd_rn(__fmul_rn(d1, h), cy);
  float pw = __fmul_rn(expf(dw), w);
  float ph = __fmul_rn(expf(dh), h);
  float x1 = __fsub_rn(pcx, __fmul_rn(0.5f, pw));
  float y1 = __fsub_rn(pcy, __fmul_rn(0.5f, ph));
  float x2 = __fadd_rn(pcx, __fmul_rn(0.5f, pw));
  float y2 = __fadd_rn(pcy, __fmul_rn(0.5f, ph));
  float x1c = fminf(fmaxf(x1, 0.0f), 1024.0f);
  float y1c = fminf(fmaxf(y1, 0.0f), 1024.0f);
  float x2c = fminf(fmaxf(x2, 0.0f), 1024.0f);
  float y2c = fminf(fmaxf(y2, 0.0f), 1024.0f);
  bool valid = (__fsub_rn(x2c, x1c) >= 1e-3f) && (__fsub_rn(y2c, y1c) >= 1e-3f);
  float* bp = boxP + (size_t)slot * 4;
  bp[0] = x1c; bp[1] = y1c; bp[2] = x2c; bp[3] = y2c;
  unsigned low = 0xFFFFFFFFu - (unsigned)i;   // pos asc tie-break, unique keys
  keyP[slot] = valid ? (((unsigned long long)sv << 32) | low) : (unsigned long long)low;
}

// ---------------- IoU on offset boxes, bitwise matching reference -----------------------
__device__ __forceinline__ bool iou_gt(float rx1, float ry1, float rx2, float ry2, float rar,
                                       float cx1, float cy1, float cx2, float cy2, float car) {
  float ltx = fmaxf(rx1, cx1), lty = fmaxf(ry1, cy1);
  float rbx = fminf(rx2, cx2), rby = fminf(ry2, cy2);
  float wx = fmaxf(__fsub_rn(rbx, ltx), 0.0f);
  float wy = fmaxf(__fsub_rn(rby, lty), 0.0f);
  float inter = __fmul_rn(wx, wy);
  float denom = __fadd_rn(__fsub_rn(__fadd_rn(rar, car), inter), 1e-9f);
  return __fdiv_rn(inter, denom) > 0.7f;
}

// ---- PER-LEVEL upper-triangle suppression bitmask (<=1000 boxes, 16 words/row) ---------
__global__ __launch_bounds__(64) void k_lvlmask(const float* boxP, unsigned long long* gmask) {
  int img = blockIdx.y;
  int q = blockIdx.x;                        // 0..621 per image
  int lvl, q2;
  if (q < 544) { lvl = q / 136; q2 = q - lvl * 136; }
  else         { lvl = 4;       q2 = q - 544; }
  int kk = (lvl == 4) ? 768 : 1000;
  int nch = (kk + 63) >> 6;
  int rb = 0;
  while (q2 >= nch - rb) { q2 -= nch - rb; ++rb; }    // upper-tri (rb, cb>=rb)
  int cb = rb + q2;
  int t = threadIdx.x;
  float off = __fmul_rn((float)lvl, 1025.0f);
  const float4* b4 = (const float4*)boxP + (size_t)img * K_SEL + lvl * 1000;
  __shared__ float cx1[64], cy1[64], cx2[64], cy2[64], car[64];
  int j = cb * 64 + t;
  if (j < kk) {
    float4 bb = b4[j];
    float ox1 = __fadd_rn(bb.x, off), oy1 = __fadd_rn(bb.y, off);
    float ox2 = __fadd_rn(bb.z, off), oy2 = __fadd_rn(bb.w, off);
    cx1[t] = ox1; cy1[t] = oy1; cx2[t] = ox2; cy2[t] = oy2;
    car[t] = __fmul_rn(__fsub_rn(ox2, ox1), __fsub_rn(oy2, oy1));
  }
  __syncthreads();
  int i = rb * 64 + t;
  if (i >= kk) return;
  float4 bb = b4[i];
  float rx1 = __fadd_rn(bb.x, off), ry1 = __fadd_rn(bb.y, off);
  float rx2 = __fadd_rn(bb.z, off), ry2 = __fadd_rn(bb.w, off);
  float rar = __fmul_rn(__fsub_rn(rx2, rx1), __fsub_rn(ry2, ry1));
  unsigned long long bits = 0;
  int jmax = min(64, kk - cb * 64);
  int jj0 = (rb == cb) ? t + 1 : 0;
  for (int jj = jj0; jj < jmax; ++jj) {
    if (iou_gt(rx1, ry1, rx2, ry2, rar, cx1[jj], cy1[jj], cx2[jj], cy2[jj], car[jj]))
      bits |= (1ULL << jj);
  }
  gmask[((size_t)(img * 5 + lvl) * 1000 + i) * 16 + cb] = bits;
}

// ---- per-level greedy NMS: single wave; speculative full-chunk row prefetch ------------
// launch_bounds(64,1): allow the full VGPR budget so all 16 spec loads stay in flight.
// spec[k] = one base + immediate offset k*512B -> 16 back-to-back independent loads.
__global__ __launch_bounds__(64, 1) void k_lvlnms(const unsigned long long* keyP,
                                                  const unsigned long long* gmask,
                                                  unsigned long long* keepw) {
  int p = blockIdx.x; int img = p / 5, lvl = p % 5;
  int kk = (lvl == 4) ? 768 : 1000;
  int nch = (kk + 63) >> 6;
  int t = threadIdx.x;
  int g = t >> 4, w = t & 15;
  const unsigned long long* gm = gmask + (size_t)p * 16000;
  const unsigned long long* kp = keyP + (size_t)img * K_SEL + lvl * 1000;
  unsigned long long rp = 0ULL;              // lane partial: OR over kept rows ≡ g (mod 4), word w
  int i0 = min(t, kk - 1);
  unsigned long long vpre = kp[i0];                       // prefetch chunk 0
  unsigned long long wpre = gm[(size_t)i0 * 16 + 0];
  for (int c = 0; c < nch; ++c) {
    int cbase = c * 64;
    const unsigned long long* sb = gm + (size_t)(cbase + g) * 16 + w;
    unsigned long long spec[16];
#pragma unroll
    for (int k = 0; k < 16; ++k) spec[k] = sb[k * 64];    // row cbase+4k+g, word w (imm offs)
    int i = cbase + t;
    bool inb = i < kk;
    unsigned long long validm = __ballot(inb && (vpre >> 32) != 0ULL);
    unsigned long long wself = wpre;
    int cn = (c + 1 < nch) ? c + 1 : c;                   // prefetch next chunk
    int inx = min(cn * 64 + t, kk - 1);
    vpre = kp[inx];
    wpre = gm[(size_t)inx * 16 + cn];
    unsigned long long cur = __shfl(rp, c) | __shfl(rp, 16 + c) |
                             __shfl(rp, 32 + c) | __shfl(rp, 48 + c);
    unsigned long long candm = validm & ~cur;
    unsigned long long keepm = 0ULL;
    while (candm) {
      int b = __ffsll(candm) - 1;
      keepm |= (1ULL << b);
      candm &= candm - 1;
      candm &= ~__shfl(wself, b);                         // within-chunk suppression
    }
    if (t == 0) keepw[(size_t)p * 16 + c] = keepm;
    if (c + 1 == nch) break;                              // no fold needed after last chunk
    // fold from speculative registers: pure VALU
#pragma unroll
    for (int k = 0; k < 16; ++k)
      rp |= ((keepm >> (4 * k + g)) & 1ULL) ? spec[k] : 0ULL;
    // unwritten lower-tri words (w <= c) only pollute rp words <= c, which later chunks
    // never read (cur reads word c' > c). Rows >= kk are never kept (validm). Harmless.
  }
}

// ---- merge: exact global rank of each kept box via per-level compaction + 4 binary
// ---- searches (all level key lists are descending, keys unique) ------------------------
__global__ __launch_bounds__(256) void k_merge(const unsigned long long* keyP, const float* boxP,
                                               const unsigned long long* keepw, float* out) {
  int img = blockIdx.x;
  int tid = threadIdx.x;
  __shared__ unsigned long long lkey[5000];   // level l at l*1000: compacted kept keys (desc)
  __shared__ int lpos[5000];                  // original within-image slot
  __shared__ int wp[5][17];                   // per-level word-prefix popcounts
  __shared__ unsigned long long kwS[80];
  for (int x = tid; x < 80; x += 256) {
    int lvl = x >> 4, w = x & 15;
    // lvl4 words 12..15 are never written by k_lvlnms (nch=12): zero them
    kwS[x] = (lvl == 4 && w >= 12) ? 0ULL : keepw[(size_t)img * 80 + x];
  }
  __syncthreads();
  if (tid < 5) {
    int acc = 0;
    for (int w = 0; w < 16; ++w) { wp[tid][w] = acc; acc += (int)__popcll(kwS[tid * 16 + w]); }
    wp[tid][16] = acc;
  }
  __syncthreads();
  const unsigned long long* kp = keyP + (size_t)img * K_SEL;
  for (int i = tid; i < K_SEL; i += 256) {
    int lvl = (i < 4000) ? i / 1000 : 4;
    int li = i - lvl * 1000;
    unsigned long long wmask = kwS[lvl * 16 + (li >> 6)];
    if ((wmask >> (li & 63)) & 1ULL) {
      int j = wp[lvl][li >> 6] + (int)__popcll(wmask & ((1ULL << (li & 63)) - 1ULL));
      lkey[lvl * 1000 + j] = kp[i];
      lpos[lvl * 1000 + j] = i;
    }
  }
  __syncthreads();
  const float4* b4 = (const float4*)boxP + (size_t)img * K_SEL;
  float4* out4 = (float4*)out + (size_t)img * 1000;
  for (int x = tid; x < 5000; x += 256) {
    int l = x / 1000, j = x - l * 1000;
    if (j >= wp[l][16]) continue;
    unsigned long long key = lkey[x];
    int grank = j;
#pragma unroll
    for (int l2 = 0; l2 < 5; ++l2) {
      if (l2 == l) continue;
      int lo = 0, hi = wp[l2][16];
      const unsigned long long* a = &lkey[l2 * 1000];
      while (lo < hi) { int mid = (lo + hi) >> 1; if (a[mid] > key) lo = mid + 1; else hi = mid; }
      grank += lo;                            // count of keys > key in level l2
    }
    if (grank < 1000) out4[grank] = b4[lpos[x]];
  }
  int KT = wp[0][16] + wp[1][16] + wp[2][16] + wp[3][16] + wp[4][16];
  for (int s = min(KT, 1000) + tid; s < 1000; s += 256)
    out4[s] = make_float4(0.f, 0.f, 0.f, 0.f);            // zero-pad tail
}

extern "C" void kernel_launch(void* const* d_in, const int* in_sizes, int n_in,
                              void* d_out, int out_size, void* d_ws, size_t ws_size,
                              hipStream_t stream) {
  (void)in_sizes; (void)n_in;
  // setup_inputs() dict order is INTERLEAVED: obj_l0, delta_l0, obj_l1, delta_l1, ..., anchors
  P5 obj, del;
  for (int i = 0; i < 5; ++i) {
    obj.p[i] = (const float*)d_in[2 * i];
    del.p[i] = (const float*)d_in[2 * i + 1];
  }
  const float* anchors = (const float*)d_in[10];
  float* out = (float*)d_out;
  char* ws = (char*)d_ws;

  // ws layout (bytes)
  unsigned* cnt               = (unsigned*)(ws + 0);                   // 160
  int* Bthr                   = (int*)(ws + 192);                      // 160
  unsigned long long* candK   = (unsigned long long*)(ws + 512);       // 40*16384*8 = 5242880 -> 5243392
  unsigned* selSV             = (unsigned*)(ws + 5243392);             // 152576 -> 5395968
  unsigned* selIdx            = (unsigned*)(ws + 5395968);             // 152576 -> 5548544
  float* boxP                 = (float*)(ws + 5548544);                // 610304 -> 6158848
  unsigned long long* keyP    = (unsigned long long*)(ws + 6158848);   // 305152 -> 6464000
  unsigned long long* keepw   = (unsigned long long*)(ws + 6464000);   // 5120   -> 6469120
  unsigned long long* gmask   = (unsigned long long*)(ws + 6469120);   // 40*1000*16*8 = 5120000 -> 11589120
  unsigned* phist             = (unsigned*)(ws + 6469120);             // overlay on gmask (dead before k_lvlmask): 5242880 -> 11712000
  const size_t NEED = 11712000ULL;
  if (ws_size < NEED) { hipMemsetAsync(d_out, 0, (size_t)out_size * 4, stream); return; }

  k_hist    <<<dim3(8, 40), 256, 0, stream>>>(obj, phist);
  k_thresh  <<<40, 256, 0, stream>>>(phist, Bthr, cnt);
  k_gather  <<<dim3(32, 40), 256, 0, stream>>>(obj, Bthr, cnt, candK);
  k_select  <<<dim3(64, 40), 256, 0, stream>>>(cnt, candK, selSV, selIdx);
  k_decode  <<<dim3(19, 8), 256, 0, stream>>>(del, anchors, selSV, selIdx, boxP, keyP);
  k_lvlmask <<<dim3(622, 8), 64, 0, stream>>>(boxP, gmask);
  k_lvlnms  <<<40, 64, 0, stream>>>(keyP, gmask, keepw);
  k_merge   <<<8, 256, 0, stream>>>(keyP, boxP, keepw, out);
}